// Round 7
// baseline (95.944 us; speedup 1.0000x reference)
//
#include <hip/hip_runtime.h>
#include <hip/hip_bf16.h>

typedef unsigned short u16;
typedef __attribute__((ext_vector_type(8))) short short8;    // 8 bf16 (4 VGPR) MFMA A/B frag
typedef __attribute__((ext_vector_type(4))) float f32x4;     // MFMA C/D frag
typedef __attribute__((ext_vector_type(8))) unsigned short u16x8;

#define MDIM 4096
#define NDIM 1024
#define KDIM 2048
#define BM 128       // rows per block
#define BNS 32       // spatial cols per block (x4 gates = 128 effective N)
#define BK 64
#define NT (KDIM / BK)   // 32 K-tiles

#define G_I 0
#define G_F 1
#define G_C 2
#define G_O 3

// fp32 -> bf16 round-to-nearest-even
static __device__ __forceinline__ u16 f2b(float f) {
    unsigned u = __builtin_bit_cast(unsigned, f);
    unsigned r = u + 0x7fffu + ((u >> 16) & 1u);
    return (u16)(r >> 16);
}

static __device__ __forceinline__ float sigm(float x) {
    return 1.0f / (1.0f + __expf(-x));
}

// async global->LDS 16B copy. LDS dest wave-uniform; HW adds lane*16.
static __device__ __forceinline__ void gload16(const void* g, void* l) {
    __builtin_amdgcn_global_load_lds(
        (__attribute__((address_space(1))) void*)g,
        (__attribute__((address_space(3))) void*)l, 16, 0, 0);
}

// inline-asm LDS read: opaque to compiler aliasing -> compiler cannot insert
// vmcnt(0) against in-flight global_load_lds. Pair cluster with counted
// s_waitcnt lgkmcnt + sched_barrier(0) before the consuming MFMA (rule #18).
template <int IMM>
static __device__ __forceinline__ short8 ds_read_imm(unsigned addr) {
    short8 r;
    asm volatile("ds_read_b128 %0, %1 offset:%2"
                 : "=&v"(r) : "v"(addr), "i"(IMM));
    return r;
}

// ---------------------------------------------------------------------------
// Pack x,h -> bf16 xh workspace, tiled [mblk 32][kblk 32][128][64] with XOR
// slot swizzle: element (row,k) at row*64 + (((k>>3)^row)&7)*8 + (k&7)
// ---------------------------------------------------------------------------
__global__ void conv_xh_kernel(const float* __restrict__ x,
                               const float* __restrict__ h,
                               u16* __restrict__ xh_ws) {
    const int kblk = blockIdx.x;  // 0..31
    const int mblk = blockIdx.y;  // 0..31
    u16* dst = xh_ws + (size_t)(mblk * 32 + kblk) * (BM * BK);
    const float* src0;
    int kofs;
    if (kblk < 16) { src0 = x; kofs = kblk * 64; }
    else           { src0 = h; kofs = kblk * 64 - 1024; }
    for (int i = threadIdx.x; i < BM * 8; i += 256) {
        int mr = i >> 3, s = i & 7;
        const float* p = src0 + (size_t)(mblk * BM + mr) * 1024 + kofs + s * 8;
        float4 a = reinterpret_cast<const float4*>(p)[0];
        float4 b = reinterpret_cast<const float4*>(p)[1];
        u16x8 o;
        o[0] = f2b(a.x); o[1] = f2b(a.y); o[2] = f2b(a.z); o[3] = f2b(a.w);
        o[4] = f2b(b.x); o[5] = f2b(b.y); o[6] = f2b(b.z); o[7] = f2b(b.w);
        *reinterpret_cast<u16x8*>(dst + mr * 64 + ((s ^ (mr & 7)) << 3)) = o;
    }
}

// ---------------------------------------------------------------------------
// Transpose-convert W_g [K][N] fp32 -> bf16 [g][nblk 32][kblk 32][32 n][64 k],
// same XOR slot swizzle on the k axis within each 64-row.
// ---------------------------------------------------------------------------
__global__ void conv_w_kernel(const float* __restrict__ Wi,
                              const float* __restrict__ Wf,
                              const float* __restrict__ Wc,
                              const float* __restrict__ Wo,
                              u16* __restrict__ w_ws) {
    const int kblk = blockIdx.x;  // 0..31
    const int nblk = blockIdx.y;  // 0..31
    const int g    = blockIdx.z;  // 0..3
    const float* W = (g == 0) ? Wi : (g == 1) ? Wf : (g == 2) ? Wc : Wo;
    u16* dst = w_ws + (size_t)((g * 32 + nblk) * 32 + kblk) * (BNS * BK);
    const int nr = threadIdx.x & 31;   // n-row within tile
    const int s  = threadIdx.x >> 5;   // k-slot 0..7
    const int n  = nblk * 32 + nr;
    const float* p = W + (size_t)(kblk * 64 + s * 8) * 1024 + n;
    u16x8 o;
#pragma unroll
    for (int j = 0; j < 8; ++j) o[j] = f2b(p[(size_t)j * 1024]);
    *reinterpret_cast<u16x8*>(dst + nr * 64 + ((s ^ (nr & 7)) << 3)) = o;
}

// ---------------------------------------------------------------------------
// Fused 4-gate GEMM + LSTM epilogue. 256 thr (4 waves = 2M x 2N), tile
// 128m x 32n x 4g, BK=64. Double-buffered 64 KiB LDS -> 2 blocks/CU.
// Schedule (T3 minimum): STAGE(t+1) -> vmcnt(8) [drains only stage(t)] ->
// barrier -> compute(t) [asm ds_read + lgkm(0) + 32 MFMA] -> barrier.
// Stage(t+1)'s DMA transfer overlaps compute(t)'s MFMA window.
// ---------------------------------------------------------------------------
__global__ __launch_bounds__(256, 2) void lstm_gemm_kernel(
    const u16* __restrict__ xh_ws, const u16* __restrict__ w_ws,
    const float* __restrict__ c_in,
    const float* __restrict__ b_i, const float* __restrict__ b_f,
    const float* __restrict__ b_c, const float* __restrict__ b_o,
    float* __restrict__ h_out, float* __restrict__ c_out) {
    // per buffer: A[128][64] (8192 u16) + B[4][32][64] (8192 u16); x2 = 64 KiB
    __shared__ u16 lds[2 * 16384];

    const int nblk = blockIdx.x;   // 0..31
    const int mblk = blockIdx.y;   // 0..31
    const int t    = threadIdx.x;
    const int lane = t & 63;
    const int w    = t >> 6;       // 0..3
    const int wm   = w >> 1;       // m-half 0..1 (64 rows)
    const int wn   = w & 1;        // n-half 0..1 (16 cols)
    const int l15  = lane & 15;
    const int l4   = lane >> 4;

    // staging: wave w stages A rows [w*32, w*32+32) and B gate w
    const u16* aS = xh_ws + (size_t)(mblk * 32) * 8192 + w * 2048 + lane * 8;
    const u16* bS = w_ws + (size_t)((w * 32 + nblk) * 32) * 2048 + lane * 8;
    u16* aD = lds + w * 2048;              // + c*16384, + i*512
    u16* bD = lds + 8192 + w * 2048;       // + c*16384, + i*512

    // asm ds_read byte-address registers (swizzle folded into slot)
    const unsigned lbase = (unsigned)(uintptr_t)&lds[0];
    unsigned slotv[2];
    slotv[0] = (unsigned)((((0 * 4 + l4) ^ l15) & 7) * 16);
    slotv[1] = (unsigned)((((1 * 4 + l4) ^ l15) & 7) * 16);
    unsigned aReg[2][2], bReg[2][2];       // [buf c][ks], literal-indexed
#pragma unroll
    for (int c = 0; c < 2; ++c)
#pragma unroll
        for (int ks = 0; ks < 2; ++ks) {
            aReg[c][ks] = lbase + c * 32768 + (wm * 64 + l15) * 128 + slotv[ks];
            bReg[c][ks] = lbase + c * 32768 + 16384 + (wn * 16 + l15) * 128 + slotv[ks];
        }

    f32x4 acc[4][4] = {};                  // [gate][mf]

#define STAGE(c, kt)                                                           \
    { const u16* as_ = aS + (size_t)(kt) * 8192;                               \
      const u16* bs_ = bS + (size_t)(kt) * 2048;                               \
      u16* ad_ = aD + (c) * 16384;                                             \
      u16* bd_ = bD + (c) * 16384;                                             \
      gload16(as_, ad_);                gload16(as_ + 512, ad_ + 512);         \
      gload16(as_ + 1024, ad_ + 1024);  gload16(as_ + 1536, ad_ + 1536);       \
      gload16(bs_, bd_);                gload16(bs_ + 512, bd_ + 512);         \
      gload16(bs_ + 1024, bd_ + 1024);  gload16(bs_ + 1536, bd_ + 1536); }

#define VMW(N) asm volatile("s_waitcnt vmcnt(" #N ")" ::: "memory")
#define BAR __builtin_amdgcn_s_barrier()
#define SB0 __builtin_amdgcn_sched_barrier(0)

// compute one K-tile out of buffer c (literal 0/1): 16 asm ds_read_b128,
// counted drain, 32 MFMA.
#define COMPUTE(c)                                                             \
    { short8 afr[4][2], bfr[4][2];                                             \
      afr[0][0] = ds_read_imm<0>(aReg[c][0]);                                  \
      afr[1][0] = ds_read_imm<2048>(aReg[c][0]);                               \
      afr[2][0] = ds_read_imm<4096>(aReg[c][0]);                               \
      afr[3][0] = ds_read_imm<6144>(aReg[c][0]);                               \
      afr[0][1] = ds_read_imm<0>(aReg[c][1]);                                  \
      afr[1][1] = ds_read_imm<2048>(aReg[c][1]);                               \
      afr[2][1] = ds_read_imm<4096>(aReg[c][1]);                               \
      afr[3][1] = ds_read_imm<6144>(aReg[c][1]);                               \
      bfr[0][0] = ds_read_imm<0>(bReg[c][0]);                                  \
      bfr[1][0] = ds_read_imm<4096>(bReg[c][0]);                               \
      bfr[2][0] = ds_read_imm<8192>(bReg[c][0]);                               \
      bfr[3][0] = ds_read_imm<12288>(bReg[c][0]);                              \
      bfr[0][1] = ds_read_imm<0>(bReg[c][1]);                                  \
      bfr[1][1] = ds_read_imm<4096>(bReg[c][1]);                               \
      bfr[2][1] = ds_read_imm<8192>(bReg[c][1]);                               \
      bfr[3][1] = ds_read_imm<12288>(bReg[c][1]);                              \
      asm volatile("s_waitcnt lgkmcnt(0)" ::: "memory");                       \
      SB0;                                                                     \
      __builtin_amdgcn_s_setprio(1);                                           \
      _Pragma("unroll") for (int ks = 0; ks < 2; ++ks)                         \
      _Pragma("unroll") for (int g = 0; g < 4; ++g)                            \
      _Pragma("unroll") for (int mf = 0; mf < 4; ++mf)                         \
          acc[g][mf] = __builtin_amdgcn_mfma_f32_16x16x32_bf16(                \
              afr[mf][ks], bfr[g][ks], acc[g][mf], 0, 0, 0);                   \
      __builtin_amdgcn_s_setprio(0);                                           \
      SB0; }

    // ---- prologue: stage tile 0 into buffer 0 ----
    STAGE(0, 0);
    VMW(0);
    BAR;

#pragma unroll 1
    for (int ut = 0; ut < 16; ++ut) {
        const int kt0 = ut * 2;
        // even K-tile (buffer 0); always a next tile to stage
        STAGE(1, kt0 + 1);
        VMW(8);            // drains stage(kt0) only; stage(kt0+1) in flight
        BAR;
        COMPUTE(0)
        BAR;
        // odd K-tile (buffer 1)
        if (ut < 15) { STAGE(0, kt0 + 2); VMW(8); }
        else         { VMW(0); }
        BAR;
        COMPUTE(1)
        BAR;
    }

    // ---- fused LSTM epilogue ----
    const int mBase = mblk * BM + wm * 64;
    const int n = nblk * BNS + wn * 16 + l15;
    const float vbi = b_i[n], vbf = b_f[n], vbc = b_c[n], vbo = b_o[n];
#pragma unroll
    for (int mf = 0; mf < 4; ++mf) {
#pragma unroll
        for (int r = 0; r < 4; ++r) {
            int m = mBase + mf * 16 + l4 * 4 + r;
            size_t idx = (size_t)m * NDIM + n;
            float gi = sigm(acc[G_I][mf][r] + vbi);
            float gf = sigm(acc[G_F][mf][r] + vbf);
            float gc = tanhf(acc[G_C][mf][r] + vbc);
            float go = sigm(acc[G_O][mf][r] + vbo);
            float ct = gf * c_in[idx] + gi * gc;
            h_out[idx] = go * tanhf(ct);
            c_out[idx] = ct;
        }
    }
#undef STAGE
#undef VMW
#undef BAR
#undef SB0
#undef COMPUTE
}

extern "C" void kernel_launch(void* const* d_in, const int* in_sizes, int n_in,
                              void* d_out, int out_size, void* d_ws, size_t ws_size,
                              hipStream_t stream) {
    const float* x   = (const float*)d_in[0];
    const float* h   = (const float*)d_in[1];
    const float* c   = (const float*)d_in[2];
    const float* Wi  = (const float*)d_in[3];
    const float* Wf  = (const float*)d_in[4];
    const float* Wc  = (const float*)d_in[5];
    const float* Wo  = (const float*)d_in[6];
    const float* bi  = (const float*)d_in[7];
    const float* bf_ = (const float*)d_in[8];
    const float* bc  = (const float*)d_in[9];
    const float* bo  = (const float*)d_in[10];

    float* hout = (float*)d_out;
    float* cout = hout + (size_t)MDIM * NDIM;

    u16* xh_ws = (u16*)d_ws;                       // bf16 xh, 16.78 MB
    u16* w_ws  = xh_ws + (size_t)MDIM * KDIM;      // bf16 W^T, 16.78 MB

    conv_xh_kernel<<<dim3(32, 32), 256, 0, stream>>>(x, h, xh_ws);
    conv_w_kernel<<<dim3(32, 32, 4), 256, 0, stream>>>(Wi, Wf, Wc, Wo, w_ws);
    lstm_gemm_kernel<<<dim3(32, 32), 256, 0, stream>>>(
        xh_ws, w_ws, c, bi, bf_, bc, bo, hout, cout);
}